// Round 8
// baseline (37.037 us; speedup 1.0000x reference)
//
#include <hip/hip_runtime.h>
#include <cmath>

static constexpr float kT = 0.55f;
static constexpr float kC = kT / (1.0f + kT);
static constexpr int MAXG = 24;   // G = 24 (compile-time unroll)
static constexpr int APT  = 2;    // anchors per thread
static constexpr int BLK  = 256;  // 4 waves/block; 2048 blocks -> 8 blocks/CU -> 100% occ
static constexpr int NW   = BLK / 64;

__global__ __launch_bounds__(BLK, 8) void loss_main_kernel(
    const float4* __restrict__ boxes,    // [B, A] float4
    const float*  __restrict__ classes,  // [B, A]
    const float4* __restrict__ anchors,  // [A] float4
    const float4* __restrict__ gtv,      // [B, G] float4
    const int*    __restrict__ nobj,     // [B]
    float4* __restrict__ ws4,            // [B * nblk * NW] (bce, coord, cnt, 0)
    int A, int G, int B)
{
    const int b   = blockIdx.y;
    const int tid = threadIdx.x;
    const int t0  = (blockIdx.x * BLK + tid) * APT;   // first anchor (A % (BLK*APT) == 0)

    // stage gt + threshold in LDS once: g-loop reads are 1x ds_read_b128 + 1x ds_read_b32
    __shared__ float4 sgt[MAXG];
    __shared__ float  sthr[MAXG];
    if (tid < MAXG) {
        const int gg = (tid < G) ? tid : (G - 1);
        const float4 v = gtv[b * G + gg];
        sgt[tid]  = v;
        sthr[tid] = kC * ((v.z - v.x) * (v.w - v.y));
    }
    const int n = nobj[b];                            // wave-uniform scalar load
    const unsigned valid = (n >= 32) ? 0xffffffffu : ((1u << n) - 1u);
    __syncthreads();

    float4   an[APT];
    float    ca[APT];
    unsigned mask[APT];
    #pragma unroll
    for (int j = 0; j < APT; ++j) {
        an[j]   = anchors[t0 + j];
        ca[j]   = kC * ((an[j].z - an[j].x) * (an[j].w - an[j].y));
        mask[j] = 0u;
    }
    const float2 xv = reinterpret_cast<const float2*>(classes)[(b * A + t0) >> 1];
    float x[APT] = { xv.x, xv.y };

    // IoU. Single clamp suffices: thr > 0, iw==0 fails, iw>0 & ih<0 -> negative fails.
    #pragma unroll
    for (int g = 0; g < MAXG; ++g) {
        const float4 gv  = sgt[g];
        const float  thr = sthr[g];
        #pragma unroll
        for (int j = 0; j < APT; ++j) {
            const float iw = fmaxf(fminf(an[j].z, gv.z) - fmaxf(an[j].x, gv.x), 0.0f);
            const float ih = fminf(an[j].w, gv.w) - fmaxf(an[j].y, gv.y);
            if (__builtin_fmaf(iw, ih, -ca[j]) >= thr) mask[j] |= (1u << g);
        }
    }

    float bce = 0.0f, coord = 0.0f;
    int cnt = 0;

    #pragma unroll
    for (int j = 0; j < APT; ++j) {
        mask[j] &= valid;
        cnt += __popc(mask[j]);
        const float ax = fabsf(x[j]);
        bce += fmaxf(x[j], 0.0f) + __logf(1.0f + __expf(-ax))
               - (mask[j] ? x[j] : 0.0f);
        if (mask[j]) {  // sparse: gather box only for positive anchors
            const float4 bx = boxes[b * A + t0 + j];
            unsigned m = mask[j];
            while (m) {
                const int g = __ffs(m) - 1;
                m &= m - 1;
                const float4 gv = sgt[g];
                float d, ad;
                d = bx.x - gv.x; ad = fabsf(d); coord += (ad < 1.0f) ? 0.5f*d*d : ad - 0.5f;
                d = bx.y - gv.y; ad = fabsf(d); coord += (ad < 1.0f) ? 0.5f*d*d : ad - 0.5f;
                d = bx.z - gv.z; ad = fabsf(d); coord += (ad < 1.0f) ? 0.5f*d*d : ad - 0.5f;
                d = bx.w - gv.w; ad = fabsf(d); coord += (ad < 1.0f) ? 0.5f*d*d : ad - 0.5f;
            }
        }
    }

    // wave64 butterfly reduce; each wave writes its own slot (no sync, no LDS hop)
    for (int off = 32; off > 0; off >>= 1) {
        bce   += __shfl_down(bce, off);
        coord += __shfl_down(coord, off);
        cnt   += __shfl_down(cnt, off);
    }
    if ((tid & 63) == 0) {
        const int slot = (b * gridDim.x + blockIdx.x) * NW + (tid >> 6);
        ws4[slot] = make_float4(bce, coord, (float)cnt, 0.0f);
    }
}

// one block, B waves; wave w reduces image w's per-wave partials (float4 slots)
__global__ void loss_final_kernel(const float4* __restrict__ ws4,
                                  float* __restrict__ out, int B, int spi)
{
    const int b    = threadIdx.x >> 6;
    const int lane = threadIdx.x & 63;

    float bce = 0.0f, coord = 0.0f, cntf = 0.0f;
    #pragma unroll 8
    for (int k = lane; k < spi; k += 64) {
        const float4 v = ws4[b * spi + k];
        bce += v.x; coord += v.y; cntf += v.z;
    }
    for (int off = 32; off > 0; off >>= 1) {
        bce   += __shfl_down(bce, off);
        coord += __shfl_down(coord, off);
        cntf  += __shfl_down(cntf, off);
    }

    __shared__ float scls[32], scrd[32];
    if (lane == 0) {
        const float np = (cntf > 0.0f) ? cntf : 1.0f;
        scls[b] = bce / np;
        scrd[b] = (cntf > 0.0f) ? coord / (4.0f * cntf) : 0.0f;
    }
    __syncthreads();
    if (threadIdx.x == 0) {
        float c = 0.0f, d = 0.0f;
        for (int i = 0; i < B; ++i) { c += scls[i]; d += scrd[i]; }
        c /= (float)B; d /= (float)B;
        out[0] = c + d;   // total_loss
        out[1] = c;       // class_loss
        out[2] = d;       // coord_loss
    }
}

extern "C" void kernel_launch(void* const* d_in, const int* in_sizes, int n_in,
                              void* d_out, int out_size, void* d_ws, size_t ws_size,
                              hipStream_t stream) {
    const float4* boxes   = (const float4*)d_in[0];
    const float*  classes = (const float*)d_in[1];
    const float4* anchors = (const float4*)d_in[2];
    const float4* gtv     = (const float4*)d_in[3];
    const int*    nobj    = (const int*)d_in[4];
    float* out = (float*)d_out;

    const int B = in_sizes[4];            // 16
    const int A = in_sizes[2] / 4;        // 65536 (multiple of BLK*APT = 512)
    const int G = in_sizes[3] / (4 * B);  // 24

    const int nblk = A / (BLK * APT);     // 128
    const int spi  = nblk * NW;           // slots per image = 512

    float4* ws4 = (float4*)d_ws;          // [B * spi]

    dim3 grid(nblk, B);
    loss_main_kernel<<<grid, BLK, 0, stream>>>(boxes, classes, anchors, gtv, nobj,
                                               ws4, A, G, B);
    loss_final_kernel<<<1, B * 64, 0, stream>>>(ws4, out, B, spi);
}

// Round 9
// 19.967 us; speedup vs baseline: 1.8549x; 1.8549x over previous
//
#include <hip/hip_runtime.h>
#include <cmath>

static constexpr float kT = 0.55f;
static constexpr float kC = kT / (1.0f + kT);
static constexpr int MAXG = 24;   // G = 24 (compile-time unroll)
static constexpr int APT  = 2;    // anchors per thread
static constexpr int BLK  = 512;  // 8 waves/block; 1024 blocks -> 4 blocks/CU -> 32 waves/CU
static constexpr int NW   = BLK / 64;

__global__ __launch_bounds__(BLK) void loss_main_kernel(
    const float4* __restrict__ boxes,    // [B, A] float4
    const float*  __restrict__ classes,  // [B, A]
    const float4* __restrict__ anchors,  // [A] float4
    const float4* __restrict__ gtv,      // [B, G] float4
    const int*    __restrict__ nobj,     // [B]
    float4* __restrict__ ws4,            // [B * nblk] (bce, coord, cnt, 0)
    int A, int G, int B)
{
    const int b   = blockIdx.y;
    const int tid = threadIdx.x;
    const int t0  = (blockIdx.x * BLK + tid) * APT;   // A % (BLK*APT) == 0

    const int n = nobj[b];                            // wave-uniform scalar load
    const unsigned valid = (n >= 32) ? 0xffffffffu : ((1u << n) - 1u);

    float4   an[APT];
    float    ca[APT];
    unsigned mask[APT];
    #pragma unroll
    for (int j = 0; j < APT; ++j) {
        an[j]   = anchors[t0 + j];
        ca[j]   = kC * ((an[j].z - an[j].x) * (an[j].w - an[j].y));
        mask[j] = 0u;
    }
    const float2 xv = reinterpret_cast<const float2*>(classes)[(b * A + t0) >> 1];
    float x[APT] = { xv.x, xv.y };

    // IoU: gt[g] wave-uniform -> s_load_dwordx4 (scalar cache, no LDS pipe).
    // Single clamp suffices: thr > 0, iw==0 fails, iw>0 & ih<0 -> negative fails.
    #pragma unroll
    for (int g = 0; g < MAXG; ++g) {
        const int gg = (g < G) ? g : 0;               // scalar clamp, bounds safety
        const float4 gv  = gtv[b * G + gg];
        const float  thr = kC * ((gv.z - gv.x) * (gv.w - gv.y));
        #pragma unroll
        for (int j = 0; j < APT; ++j) {
            const float iw = fmaxf(fminf(an[j].z, gv.z) - fmaxf(an[j].x, gv.x), 0.0f);
            const float ih = fminf(an[j].w, gv.w) - fmaxf(an[j].y, gv.y);
            if (__builtin_fmaf(iw, ih, -ca[j]) >= thr) mask[j] |= (1u << g);
        }
    }

    float bce = 0.0f, coord = 0.0f;
    int cnt = 0;

    #pragma unroll
    for (int j = 0; j < APT; ++j) {
        mask[j] &= valid;
        cnt += __popc(mask[j]);
        const float ax = fabsf(x[j]);
        bce += fmaxf(x[j], 0.0f) + __logf(1.0f + __expf(-ax))
               - (mask[j] ? x[j] : 0.0f);
        if (mask[j]) {  // sparse: gather box only for positive anchors
            const float4 bx = boxes[b * A + t0 + j];
            unsigned m = mask[j];
            while (m) {
                const int g = __ffs(m) - 1;
                m &= m - 1;
                const float4 gv = gtv[b * G + g];
                float d, ad;
                d = bx.x - gv.x; ad = fabsf(d); coord += (ad < 1.0f) ? 0.5f*d*d : ad - 0.5f;
                d = bx.y - gv.y; ad = fabsf(d); coord += (ad < 1.0f) ? 0.5f*d*d : ad - 0.5f;
                d = bx.z - gv.z; ad = fabsf(d); coord += (ad < 1.0f) ? 0.5f*d*d : ad - 0.5f;
                d = bx.w - gv.w; ad = fabsf(d); coord += (ad < 1.0f) ? 0.5f*d*d : ad - 0.5f;
            }
        }
    }

    // wave64 butterfly reduce
    for (int off = 32; off > 0; off >>= 1) {
        bce   += __shfl_down(bce, off);
        coord += __shfl_down(coord, off);
        cnt   += __shfl_down(cnt, off);
    }
    __shared__ float sb[NW], sc[NW];
    __shared__ int sn[NW];
    const int wid = tid >> 6;
    if ((tid & 63) == 0) { sb[wid] = bce; sc[wid] = coord; sn[wid] = cnt; }
    __syncthreads();
    if (tid == 0) {
        float tb = 0.0f, tc = 0.0f; int tn = 0;
        #pragma unroll
        for (int w = 0; w < NW; ++w) { tb += sb[w]; tc += sc[w]; tn += sn[w]; }
        ws4[b * gridDim.x + blockIdx.x] = make_float4(tb, tc, (float)tn, 0.0f);
    }
}

// one block, B waves; wave w reduces image w's per-block partials (1 float4/slot)
__global__ void loss_final_kernel(const float4* __restrict__ ws4,
                                  float* __restrict__ out, int B, int nblk)
{
    const int b    = threadIdx.x >> 6;
    const int lane = threadIdx.x & 63;

    float bce = 0.0f, coord = 0.0f, cntf = 0.0f;
    for (int k = lane; k < nblk; k += 64) {
        const float4 v = ws4[b * nblk + k];
        bce += v.x; coord += v.y; cntf += v.z;
    }
    for (int off = 32; off > 0; off >>= 1) {
        bce   += __shfl_down(bce, off);
        coord += __shfl_down(coord, off);
        cntf  += __shfl_down(cntf, off);
    }

    __shared__ float scls[32], scrd[32];
    if (lane == 0) {
        const float np = (cntf > 0.0f) ? cntf : 1.0f;
        scls[b] = bce / np;
        scrd[b] = (cntf > 0.0f) ? coord / (4.0f * cntf) : 0.0f;
    }
    __syncthreads();
    if (threadIdx.x == 0) {
        float c = 0.0f, d = 0.0f;
        for (int i = 0; i < B; ++i) { c += scls[i]; d += scrd[i]; }
        c /= (float)B; d /= (float)B;
        out[0] = c + d;   // total_loss
        out[1] = c;       // class_loss
        out[2] = d;       // coord_loss
    }
}

extern "C" void kernel_launch(void* const* d_in, const int* in_sizes, int n_in,
                              void* d_out, int out_size, void* d_ws, size_t ws_size,
                              hipStream_t stream) {
    const float4* boxes   = (const float4*)d_in[0];
    const float*  classes = (const float*)d_in[1];
    const float4* anchors = (const float4*)d_in[2];
    const float4* gtv     = (const float4*)d_in[3];
    const int*    nobj    = (const int*)d_in[4];
    float* out = (float*)d_out;

    const int B = in_sizes[4];            // 16
    const int A = in_sizes[2] / 4;        // 65536 (multiple of BLK*APT = 1024)
    const int G = in_sizes[3] / (4 * B);  // 24

    const int nblk = A / (BLK * APT);     // 64

    float4* ws4 = (float4*)d_ws;          // [B * nblk]

    dim3 grid(nblk, B);
    loss_main_kernel<<<grid, BLK, 0, stream>>>(boxes, classes, anchors, gtv, nobj,
                                               ws4, A, G, B);
    loss_final_kernel<<<1, B * 64, 0, stream>>>(ws4, out, B, nblk);
}